// Round 6
// baseline (1032.667 us; speedup 1.0000x reference)
//
#include <hip/hip_runtime.h>

// LSTM (B=2048, T=1024, I=8, H=64) + sigmoid(FC) — wave-autonomous, barrier-free.
//
// 2048 rows / 1024 SIMDs = 2 rows per wave. Each wave holds ALL 16 M-tiles of
// the weight matrix in registers (a0/a1/a2, 192 VGPRs -> 1 wave/SIMD, which is
// exactly the 1024 waves we need) and runs its own 2-row recurrence with NO
// __syncthreads anywhere: h is exchanged across lanes with 8 ds_bpermute per
// step (precomputed byte indices). N-cols: col nib carries row nib&1 (8
// copies); thread (g4,nib) activates 2 elements jh = 16*qq + 4*g4 + 2*rpair
// + {0,1} (qq=cp&3, rpair=cp>>2, cp=nib>>1) picked from acc by a cndmask tree.
// x staged in wave-private LDS (bf16, double-buffered per 32-step chunk);
// fx prefetched one step ahead so only the h chain is serial.
// FC epilogue via __shfl_xor butterfly (row parity preserved). Zero barriers.

namespace {
constexpr int T_LEN = 1024;
constexpr int TS    = 32;

typedef __attribute__((ext_vector_type(8))) short  short8v;
typedef __attribute__((ext_vector_type(4))) float  float4v;
typedef unsigned short u16;
typedef unsigned int   u32;
typedef unsigned long long u64;

__device__ __forceinline__ float fsig(float x) {
  return __builtin_amdgcn_rcpf(1.f + __expf(-x));
}
__device__ __forceinline__ float ftanh(float x) {
  return 1.f - 2.f * __builtin_amdgcn_rcpf(__expf(2.f * x) + 1.f);
}
__device__ __forceinline__ u16 f2bf(float f) {  // RNE
  u32 u = __float_as_uint(f);
  u32 r = ((u >> 16) & 1u) + 0x7fffu;
  return (u16)((u + r) >> 16);
}

__global__ __launch_bounds__(256, 1) void lstm_wave(
    const float* __restrict__ x,     // [B, T, 8]
    const float* __restrict__ W_ih,  // [256, 8]
    const float* __restrict__ W_hh,  // [256, 64]
    const float* __restrict__ b_ih,  // [256]
    const float* __restrict__ b_hh,  // [256]
    const float* __restrict__ fc_w,  // [64]
    const float* __restrict__ fc_b,  // [1]
    float* __restrict__ out) {       // [B]
  // wave-private x staging: [wave][buf][tt][row*8+ch] bf16 (8 KB total)
  __shared__ __align__(16) u16 xb[4][2][TS][16];

  const int tid  = threadIdx.x;
  const int lane = tid & 63;
  const int wv   = tid >> 6;
  const int g4   = lane >> 4;
  const int nib  = lane & 15;
  const int row  = nib & 1;         // this thread's batch row (of the wave's 2)
  const int cp   = nib >> 1;        // copy index 0..7
  const int qq   = cp & 3;          // which 16-block of jh
  const int rp   = cp >> 2;         // which reg-pair
  const int jh0  = 16 * qq + 4 * g4 + 2 * rp;  // owned h indices jh0, jh0+1
  const int rb   = blockIdx.x * 8 + wv * 2;    // wave's batch rows rb, rb+1

  // ---- static A fragments: ALL 16 tiles; a*[gg][q] covers gates 64gg+16q+nib
  // frag0 k=0..31 = [W_ih(8) | bias | 0...], frag1 = W_hh[:,0:32],
  // frag2 = W_hh[:,32:64].  A[m][k=8*g4+j].
  short8v a0[4][4], a1[4][4], a2[4][4];
  for (int gg = 0; gg < 4; ++gg) {
    for (int q = 0; q < 4; ++q) {
      const int n = 64 * gg + 16 * q + nib;
      short8v f0, f1, f2;
      for (int j = 0; j < 8; ++j) {
        const int k = 8 * g4 + j;
        float v0 = 0.f;
        if (k < 8) v0 = W_ih[n * 8 + k];
        else if (k == 8) v0 = b_ih[n] + b_hh[n];
        f0[j] = (short)f2bf(v0);
        f1[j] = (short)f2bf(W_hh[n * 64 + k]);
        f2[j] = (short)f2bf(W_hh[n * 64 + 32 + k]);
      }
      a0[gg][q] = f0; a1[gg][q] = f1; a2[gg][q] = f2;
    }
  }
  short8v bias_frag = {0, 0, 0, 0, 0, 0, 0, 0};
  if (g4 == 1) bias_frag[0] = (short)0x3f80;  // B[k=8][*] = 1.0
  const bool is_x = (g4 == 0);

  // ---- bpermute indices: dword dw of h holds h[2dw],h[2dw+1]; its producer
  // lane = 16*((dw>>1)&3) + 2*((dw>>3) + 4*(dw&1)) + row. We need dwords
  // 4*g4+s (fh0) and 16+4*g4+s (fh1), s=0..3.
  int idx[8];
#pragma unroll
  for (int s = 0; s < 8; ++s) {
    const int dw = (s < 4) ? (4 * g4 + s) : (16 + 4 * g4 + (s - 4));
    const int g4p = (dw >> 1) & 3, qqp = dw >> 3, rpp = dw & 1;
    idx[s] = (16 * g4p + 2 * (qqp + 4 * rpp) + row) * 4;
  }

  // ---- x staging helpers: 2 float4/lane per 32-step chunk ----
  float4v xr0, xr1;
  auto stage_load = [&](int chunk) {
    const float* src = x + (size_t)rb * (T_LEN * 8) + (size_t)chunk * (TS * 8);
    {
      const int f = lane;            // float4 idx 0..63 -> row 0
      const int r = f >> 6, m4 = f & 63;
      xr0 = *(const float4v*)&src[(size_t)r * (T_LEN * 8) + m4 * 4];
    }
    {
      const int f = lane + 64;       // 64..127 -> row 1
      const int r = f >> 6, m4 = f & 63;
      xr1 = *(const float4v*)&src[(size_t)r * (T_LEN * 8) + m4 * 4];
    }
  };
  auto stage_write = [&](int buf) {
#pragma unroll
    for (int p = 0; p < 2; ++p) {
      const float4v v = p ? xr1 : xr0;
      const int f = lane + 64 * p;
      const int r = f >> 6, m4 = f & 63;
      const int tt = m4 >> 1, chn = (m4 & 1) * 4;
      union { u64 u; u16 s[4]; } pk;
      pk.s[0] = f2bf(v[0]); pk.s[1] = f2bf(v[1]);
      pk.s[2] = f2bf(v[2]); pk.s[3] = f2bf(v[3]);
      *(u64*)&xb[wv][buf][tt][r * 8 + chn] = pk.u;
    }
  };

  // ---- prologue ----
  stage_load(0);
  stage_write(0);
  short8v fx_cur;
  {
    const short8v xv = *(const short8v*)&xb[wv][0][0][row * 8];
    fx_cur = is_x ? xv : bias_frag;
  }
  short8v fh0 = {0,0,0,0,0,0,0,0}, fh1 = {0,0,0,0,0,0,0,0};  // h(-1) = 0
  float c0 = 0.f, c1 = 0.f;
  float hA = 0.f, hB = 0.f;  // final-step h values
  const bool selq1 = (qq & 1) != 0;
  const bool selq2 = (qq & 2) != 0;
  const bool selrp = rp != 0;

  for (int ch = 0; ch < T_LEN / TS; ++ch) {
    const int buf = ch & 1;
    const bool more = (ch < T_LEN / TS - 1);
    if (more) stage_load(ch + 1);   // global -> regs, drains at stage_write
#pragma unroll 2
    for (int tt = 0; tt < TS; ++tt) {
      if (tt == 16 && more) stage_write(buf ^ 1);

      // ---- 48 MFMAs: acc[gg][q] = gates 64gg+16q+4g4+r, col nib ----
      float4v acc[4][4];
#pragma unroll
      for (int gg = 0; gg < 4; ++gg) {
#pragma unroll
        for (int q = 0; q < 4; ++q) {
          float4v a = __builtin_amdgcn_mfma_f32_16x16x32_bf16(
              a0[gg][q], fx_cur, (float4v){0.f, 0.f, 0.f, 0.f}, 0, 0, 0);
          a = __builtin_amdgcn_mfma_f32_16x16x32_bf16(a1[gg][q], fh0, a, 0, 0, 0);
          acc[gg][q] = __builtin_amdgcn_mfma_f32_16x16x32_bf16(a2[gg][q], fh1, a, 0, 0, 0);
        }
      }

      // ---- prefetch next step's fx (independent of the h chain) ----
      {
        short8v xv;
        if (tt < TS - 1) xv = *(const short8v*)&xb[wv][buf][tt + 1][row * 8];
        else             xv = *(const short8v*)&xb[wv][buf ^ 1][0][row * 8];
        fx_cur = is_x ? xv : bias_frag;
      }

      // ---- select this thread's 2 elements per gate (cndmask tree) ----
      float gv[4][2];
#pragma unroll
      for (int gg = 0; gg < 4; ++gg) {
#pragma unroll
        for (int e = 0; e < 2; ++e) {
          const float t0 = selrp ? acc[gg][0][2 + e] : acc[gg][0][e];
          const float t1 = selrp ? acc[gg][1][2 + e] : acc[gg][1][e];
          const float t2 = selrp ? acc[gg][2][2 + e] : acc[gg][2][e];
          const float t3 = selrp ? acc[gg][3][2 + e] : acc[gg][3][e];
          const float u01 = selq1 ? t1 : t0;
          const float u23 = selq1 ? t3 : t2;
          gv[gg][e] = selq2 ? u23 : u01;
        }
      }

      // ---- activation (2 elements) ----
      const float i0 = fsig(gv[0][0]), f0v = fsig(gv[1][0]);
      const float g0v = ftanh(gv[2][0]), o0 = fsig(gv[3][0]);
      c0 = f0v * c0 + i0 * g0v;
      hA = o0 * ftanh(c0);
      const float i1 = fsig(gv[0][1]), f1v = fsig(gv[1][1]);
      const float g1v = ftanh(gv[2][1]), o1 = fsig(gv[3][1]);
      c1 = f1v * c1 + i1 * g1v;
      hB = o1 * ftanh(c1);

      // ---- h-exchange: pack 2 bf16 -> dword, 8 bpermutes -> B fragments ----
      const int hdw = (int)((u32)f2bf(hA) | ((u32)f2bf(hB) << 16));
      int d[8];
#pragma unroll
      for (int s = 0; s < 8; ++s) d[s] = __builtin_amdgcn_ds_bpermute(idx[s], hdw);
      union { int i[4]; short8v v; } b0, b1;
      b0.i[0] = d[0]; b0.i[1] = d[1]; b0.i[2] = d[2]; b0.i[3] = d[3];
      b1.i[0] = d[4]; b1.i[1] = d[5]; b1.i[2] = d[6]; b1.i[3] = d[7];
      fh0 = b0.v; fh1 = b1.v;
    }
  }

  // ---- epilogue: out[rb+row] = sigmoid(sum_jh h[jh]*fc_w[jh] + fc_b) ----
  // thread's partial: hA*fcw[jh0] + hB*fcw[jh0+1]; butterfly over masks that
  // preserve lane parity (= row).
  float part = hA * fc_w[jh0] + hB * fc_w[jh0 + 1];
#pragma unroll
  for (int m = 2; m <= 32; m <<= 1) part += __shfl_xor(part, m, 64);
  if (lane < 2) out[rb + lane] = fsig(part + fc_b[0]);
}
}  // namespace

extern "C" void kernel_launch(void* const* d_in, const int* in_sizes, int n_in,
                              void* d_out, int out_size, void* d_ws,
                              size_t ws_size, hipStream_t stream) {
  const float* x    = (const float*)d_in[0];
  const float* W_ih = (const float*)d_in[1];
  const float* W_hh = (const float*)d_in[2];
  const float* b_ih = (const float*)d_in[3];
  const float* b_hh = (const float*)d_in[4];
  const float* fc_w = (const float*)d_in[5];
  const float* fc_b = (const float*)d_in[6];
  float* out = (float*)d_out;

  const int B = in_sizes[0] / (T_LEN * 8);  // 2048
  lstm_wave<<<dim3(B / 8), dim3(256), 0, stream>>>(x, W_ih, W_hh, b_ih, b_hh,
                                                   fc_w, fc_b, out);
}

// Round 7
// 548.767 us; speedup vs baseline: 1.8818x; 1.8818x over previous
//
#include <hip/hip_runtime.h>

// LSTM (B=2048, T=1024, I=8, H=64) + sigmoid(FC), bf16 MFMA.
// Round 7: per-chunk xg pre-pass (x-projection hoisted out of the recurrence).
//
// Per 8-step chunk, xg = x*W_ih^T + b is computed with 8 MFMAs/wave
// (M=256 gates, N=32 = 8tt x 4rows, K=32 [x(8)|bias|0..]) into fp32 LDS.
// The recurrent step then runs K=64 (h only): 2-deep MFMA chain with the acc
// C-INITIALIZED from xg (prefetched one step ahead, off the serial chain).
// Keeps r5's verified structure: gate-strided M-tiles (wave wv owns tiles
// {4g+wv} so acc[g] = gate-type g of jh=16wv+4g4+rsel), one-elem/thread
// in-register activation, ONE barrier/step, R=4 rows -> 512 blocks = 2/CU.
// Strides tuned so all b128 patterns tile 32 banks exactly 2x (free): xg=272dw,
// h=96 shorts. x global loads issued 2 chunks (~6000 cyc) ahead.

namespace {
constexpr int T_LEN = 1024;
constexpr int R     = 4;     // batch rows per block
constexpr int TS    = 8;     // timesteps per chunk
constexpr int NCH   = T_LEN / TS;   // 128 chunks
constexpr int XGS   = 272;   // xg stride per (tt,row) in dwords (272%32==16)
constexpr int HS    = 96;    // h stride per row in shorts (48dw%32==16)

typedef __attribute__((ext_vector_type(8))) short  short8v;
typedef __attribute__((ext_vector_type(4))) float  float4v;
typedef unsigned short u16;
typedef unsigned int   u32;

__device__ __forceinline__ float fsig(float x) {
  return __builtin_amdgcn_rcpf(1.f + __expf(-x));
}
__device__ __forceinline__ float ftanh(float x) {
  return 1.f - 2.f * __builtin_amdgcn_rcpf(__expf(2.f * x) + 1.f);
}
__device__ __forceinline__ u16 f2bf(float f) {  // RNE
  u32 u = __float_as_uint(f);
  u32 r = ((u >> 16) & 1u) + 0x7fffu;
  return (u16)((u + r) >> 16);
}

__global__ __launch_bounds__(256, 2) void lstm_xg(
    const float* __restrict__ x,     // [B, T, 8]
    const float* __restrict__ W_ih,  // [256, 8]
    const float* __restrict__ W_hh,  // [256, 64]
    const float* __restrict__ b_ih,  // [256]
    const float* __restrict__ b_hh,  // [256]
    const float* __restrict__ fc_w,  // [64]
    const float* __restrict__ fc_b,  // [1]
    float* __restrict__ out) {       // [B]
  __shared__ __align__(16) float xg_lds[TS * R * XGS];   // 34.8 KB
  __shared__ __align__(16) u16   h_lds[2][R * HS];       // 1.5 KB
  __shared__ __align__(16) u16   x_lds[2][TS * R * 8];   // 1 KB (bf16 x)
  __shared__ __align__(16) float hf[R][64];              // final h

  const int tid  = threadIdx.x;
  const int lane = tid & 63;
  const int wv   = tid >> 6;        // wave 0..3
  const int g4   = lane >> 4;       // MFMA k-quad / C row-quad
  const int nib  = lane & 15;       // MFMA m/n coord
  const int row  = nib & 3;         // batch row (cols duplicate x4)
  const int rsel = nib >> 2;        // which acc reg this thread activates
  const int jh   = 16 * wv + 4 * g4 + rsel;   // owned h index
  const int bBase = blockIdx.x * R;

  // ---- static A fragments ----
  // Recurrent (h) part: wave wv owns tiles q=4g+wv (g = gate type i,f,g,o):
  //   ah0[g] = W_hh[:,0:32], ah1[g] = W_hh[:,32:64], A[m=16q+nib][k=8g4+j].
  // xg part: axg[g] = [W_ih(8) | bias(1) | 0...] over K=32 (k>=16 zero).
  short8v ah0[4], ah1[4], axg[4];
  for (int g = 0; g < 4; ++g) {
    const int n = 16 * (4 * g + wv) + nib;  // gate row
    short8v f0, f1, fx;
    for (int j = 0; j < 8; ++j) {
      const int k = 8 * g4 + j;
      f0[j] = (short)f2bf(W_hh[n * 64 + k]);
      f1[j] = (short)f2bf(W_hh[n * 64 + 32 + k]);
      float vx = 0.f;
      if (k < 8) vx = W_ih[n * 8 + k];
      else if (k == 8) vx = b_ih[n] + b_hh[n];
      fx[j] = (short)f2bf(vx);
    }
    ah0[g] = f0; ah1[g] = f1; axg[g] = fx;
  }
  // pre-pass B constant parts: bias one-hot at k=8 (g4==1, j==0); zero else
  short8v bias_frag = {0, 0, 0, 0, 0, 0, 0, 0};
  if (g4 == 1) bias_frag[0] = (short)0x3f80;  // bf16(1.0)

  for (int i = tid; i < 2 * R * HS; i += 256) ((u16*)h_lds)[i] = 0;  // h0=0

  // ---- x staging: 1 float/thread/chunk; srow/sidx: x[bBase+srow][...] ----
  const int srow = tid >> 6, sidx = tid & 63;          // sidx = tt*8+ch
  const int stt = sidx >> 3, sch = sidx & 7;
  const size_t xoff = (size_t)(bBase + srow) * (T_LEN * 8);
  float xreg;

  // prologue: chunk0 -> x_lds[0]; chunk1 -> xreg
  x_lds[0][stt * 32 + srow * 8 + sch] = f2bf(x[xoff + sidx]);
  xreg = x[xoff + 64 + sidx];
  __syncthreads();

  // hoisted addresses
  const int xg_base = row * XGS + 16 * wv + 4 * g4;    // + g*64 + tt*4*XGS
  const int h_rd0   = row * HS + 8 * g4;
  const bool sel1 = (rsel & 1) != 0;
  const bool sel2 = (rsel & 2) != 0;

  float c = 0.f;
  float4v cinit[4];

  for (int ch = 0; ch < NCH; ++ch) {
    // ======== chunk boundary: xg pre-pass (x_lds[ch&1] is valid) ========
    {
      const u16* xb = &x_lds[ch & 1][0];
      // B-frags for the two N-tiles: col nib -> (tt = nt*4 + (nib>>2), row)
      short8v bx[2];
#pragma unroll
      for (int nt = 0; nt < 2; ++nt) {
        const int tt = nt * 4 + (nib >> 2);
        const short8v xv = *(const short8v*)&xb[tt * 32 + row * 8];
        bx[nt] = (g4 == 0) ? xv : bias_frag;   // g4>=2 rows of A are zero too
      }
#pragma unroll
      for (int g = 0; g < 4; ++g) {
#pragma unroll
        for (int nt = 0; nt < 2; ++nt) {
          const float4v cxg = __builtin_amdgcn_mfma_f32_16x16x32_bf16(
              axg[g], bx[nt], (float4v){0.f, 0.f, 0.f, 0.f}, 0, 0, 0);
          const int tt = nt * 4 + (nib >> 2);
          *(float4v*)&xg_lds[tt * (4 * XGS) + xg_base + 64 * g] = cxg;
        }
      }
      // stage x: write chunk ch+1, load chunk ch+2 (2-chunk lookahead)
      if (ch + 1 < NCH)
        x_lds[(ch + 1) & 1][stt * 32 + srow * 8 + sch] = f2bf(xreg);
      if (ch + 2 < NCH) xreg = x[xoff + (size_t)(ch + 2) * 64 + sidx];
    }
    __syncthreads();  // xg visible

    // cinit for tt=0 (on-chain once per chunk)
#pragma unroll
    for (int g = 0; g < 4; ++g)
      cinit[g] = *(const float4v*)&xg_lds[xg_base + 64 * g];

    // ======== 8 recurrent steps ========
#pragma unroll
    for (int tt = 0; tt < TS; ++tt) {
      const int t = ch * TS + tt;
      const int hb = t & 1;

      // chain: h read -> 2-deep MFMA
      const short8v fh0 = *(const short8v*)&h_lds[hb][h_rd0];
      const short8v fh1 = *(const short8v*)&h_lds[hb][h_rd0 + 32];

      // prefetch next step's cinit (off-chain)
      float4v cnext[4];
      if (tt < TS - 1) {
#pragma unroll
        for (int g = 0; g < 4; ++g)
          cnext[g] =
              *(const float4v*)&xg_lds[(tt + 1) * (4 * XGS) + xg_base + 64 * g];
      }

      float4v acc[4];
#pragma unroll
      for (int g = 0; g < 4; ++g) {
        float4v a = __builtin_amdgcn_mfma_f32_16x16x32_bf16(ah0[g], fh0,
                                                            cinit[g], 0, 0, 0);
        acc[g] = __builtin_amdgcn_mfma_f32_16x16x32_bf16(ah1[g], fh1, a, 0, 0, 0);
      }

      // select this thread's element per gate (2-level cndmask tree)
      float gv[4];
#pragma unroll
      for (int g = 0; g < 4; ++g) {
        const float x01 = sel1 ? acc[g][1] : acc[g][0];
        const float x23 = sel1 ? acc[g][3] : acc[g][2];
        gv[g] = sel2 ? x23 : x01;
      }
      const float iv = fsig(gv[0]);
      const float fv = fsig(gv[1]);
      const float gg = ftanh(gv[2]);
      const float ov = fsig(gv[3]);
      c = fv * c + iv * gg;
      const float h = ov * ftanh(c);
      h_lds[hb ^ 1][row * HS + jh] = f2bf(h);
      if (t == T_LEN - 1) hf[row][jh] = h;

#pragma unroll
      for (int g = 0; g < 4; ++g) cinit[g] = cnext[g];
      __syncthreads();  // the one barrier per step
    }
  }

  // ---- epilogue: out[b] = sigmoid(hT . fc_w + fc_b) ----
  if (tid < R) {
    float a = fc_b[0];
#pragma unroll
    for (int k = 0; k < 64; ++k) a += hf[tid][k] * fc_w[k];
    out[bBase + tid] = fsig(a);
  }
}
}  // namespace

extern "C" void kernel_launch(void* const* d_in, const int* in_sizes, int n_in,
                              void* d_out, int out_size, void* d_ws,
                              size_t ws_size, hipStream_t stream) {
  const float* x    = (const float*)d_in[0];
  const float* W_ih = (const float*)d_in[1];
  const float* W_hh = (const float*)d_in[2];
  const float* b_ih = (const float*)d_in[3];
  const float* b_hh = (const float*)d_in[4];
  const float* fc_w = (const float*)d_in[5];
  const float* fc_b = (const float*)d_in[6];
  float* out = (float*)d_out;

  const int B = in_sizes[0] / (T_LEN * 8);  // 2048
  lstm_xg<<<dim3(B / R), dim3(256), 0, stream>>>(x, W_ih, W_hh, b_ih, b_hh,
                                                 fc_w, fc_b, out);
}